// Round 2
// baseline (1617.490 us; speedup 1.0000x reference)
//
#include <hip/hip_runtime.h>
#include <math.h>

typedef unsigned short u16;
typedef __bf16 bf16;
typedef bf16 v8bf __attribute__((ext_vector_type(8)));
typedef float v4f __attribute__((ext_vector_type(4)));

__device__ __forceinline__ float b2f(u16 u) {
    union { float f; unsigned v; } x;
    x.v = ((unsigned)u) << 16;
    return x.f;
}
__device__ __forceinline__ u16 f2b(float f) {
    union { float f; unsigned v; } x;
    x.f = f;
    unsigned v = x.v;
    return (u16)((v + 0x7FFFu + ((v >> 16) & 1u)) >> 16);  // RNE
}

union Frag { v8bf b; u16 s[8]; };

// split 8 contiguous f32 into hi/lo bf16 fragments
__device__ __forceinline__ void split8(const float* __restrict__ p, v8bf& hi, v8bf& lo) {
    Frag h, l;
#pragma unroll
    for (int j = 0; j < 8; ++j) {
        float v = p[j];
        u16 a = f2b(v);
        h.s[j] = a;
        l.s[j] = f2b(v - b2f(a));
    }
    hi = h.b; lo = l.b;
}

// ---------------------------------------------------------------------------
// hidden f32 -> hf (f32 copy) + hhi/hlo (bf16 split)
// ---------------------------------------------------------------------------
__global__ void prep_h(const float* __restrict__ hid, float* __restrict__ hf,
                       u16* __restrict__ hhi, u16* __restrict__ hlo) {
    int i = blockIdx.x * 256 + threadIdx.x;  // 65536
    float v = hid[i];
    hf[i] = v;
    u16 h = f2b(v);
    hhi[i] = h;
    hlo[i] = f2b(v - b2f(h));
}

// ---------------------------------------------------------------------------
// Transpose f32 [R][C] -> bf16 hi/lo [C][R]
// ---------------------------------------------------------------------------
__global__ void transpose_split(const float* __restrict__ src, u16* __restrict__ dhi,
                                u16* __restrict__ dlo, int R, int C) {
    __shared__ float tile[32][33];
    int tid = threadIdx.x;
    int tx = tid & 31, ty = tid >> 5;
    int c0 = blockIdx.x * 32, r0 = blockIdx.y * 32;
#pragma unroll
    for (int i = 0; i < 4; ++i)
        tile[ty + i * 8][tx] = src[(size_t)(r0 + ty + i * 8) * C + c0 + tx];
    __syncthreads();
#pragma unroll
    for (int i = 0; i < 4; ++i) {
        int c = c0 + ty + i * 8;
        float v = tile[tx][ty + i * 8];
        u16 h = f2b(v);
        size_t o = (size_t)c * R + r0 + tx;
        dhi[o] = h;
        dlo[o] = f2b(v - b2f(h));
    }
}

// ---------------------------------------------------------------------------
// xin = E[x] @ W + b0, split-bf16, stored as hi/lo bf16 planes.
// Wave computes 64x64 (4x4 MFMA tiles). Grid 1536 x 256.
// ---------------------------------------------------------------------------
__global__ __launch_bounds__(256) void xin_kernel(
        const int* __restrict__ x, const float* __restrict__ E,
        const u16* __restrict__ WThi, const u16* __restrict__ WTlo,
        const float* __restrict__ b0, u16* __restrict__ xhi, u16* __restrict__ xlo) {
    int tid = threadIdx.x;
    int wave = tid >> 6, lane = tid & 63;
    int n = lane & 15, q = lane >> 4;
    int wid = blockIdx.x * 4 + wave;   // 6144 waves
    int bt0 = (wid / 48) * 64;         // 128 bt-blocks
    int j0 = (wid % 48) * 64;          // 48 j-blocks

    const float* arow[4];
#pragma unroll
    for (int mt = 0; mt < 4; ++mt)
        arow[mt] = E + (size_t)x[bt0 + mt * 16 + n] * 256 + q * 8;
    const u16* bhp[4];
    const u16* blp[4];
#pragma unroll
    for (int nt = 0; nt < 4; ++nt) {
        size_t r = (size_t)(j0 + nt * 16 + n) * 256 + q * 8;
        bhp[nt] = WThi + r;
        blp[nt] = WTlo + r;
    }

    v4f acc[4][4];
#pragma unroll
    for (int mt = 0; mt < 4; ++mt)
#pragma unroll
        for (int nt = 0; nt < 4; ++nt) acc[mt][nt] = (v4f){0.f, 0.f, 0.f, 0.f};

    for (int kk = 0; kk < 8; ++kk) {
        v8bf Bh[4], Bl[4];
#pragma unroll
        for (int nt = 0; nt < 4; ++nt) {
            Bh[nt] = *(const v8bf*)(bhp[nt] + kk * 32);
            Bl[nt] = *(const v8bf*)(blp[nt] + kk * 32);
        }
#pragma unroll
        for (int mt = 0; mt < 4; ++mt) {
            v8bf Ah, Al;
            split8(arow[mt] + kk * 32, Ah, Al);
#pragma unroll
            for (int nt = 0; nt < 4; ++nt) {
                acc[mt][nt] = __builtin_amdgcn_mfma_f32_16x16x32_bf16(Ah, Bh[nt], acc[mt][nt], 0, 0, 0);
                acc[mt][nt] = __builtin_amdgcn_mfma_f32_16x16x32_bf16(Ah, Bl[nt], acc[mt][nt], 0, 0, 0);
                acc[mt][nt] = __builtin_amdgcn_mfma_f32_16x16x32_bf16(Al, Bh[nt], acc[mt][nt], 0, 0, 0);
            }
        }
    }
#pragma unroll
    for (int mt = 0; mt < 4; ++mt)
#pragma unroll
        for (int nt = 0; nt < 4; ++nt) {
            int j = j0 + nt * 16 + n;
            float bj = b0[j];
#pragma unroll
            for (int r = 0; r < 4; ++r) {
                int bt = bt0 + mt * 16 + q * 4 + r;
                float v = acc[mt][nt][r] + bj;
                u16 h = f2b(v);
                size_t o = (size_t)bt * 3072 + j;
                xhi[o] = h;
                xlo[o] = f2b(v - b2f(h));
            }
        }
}

// ---------------------------------------------------------------------------
// One GRU step. 256 blocks = 4 b-tiles x 64 u-tiles, 4 waves split K=1024.
// Split-bf16: rec = hh*Uh + hh*Ul + hl*Uh per gate.
// ---------------------------------------------------------------------------
__global__ __launch_bounds__(256) void step_kernel(
        int t, const u16* __restrict__ xhi, const u16* __restrict__ xlo,
        const u16* __restrict__ UThi, const u16* __restrict__ UTlo,
        const float* __restrict__ b1,
        const u16* __restrict__ hhi_in, const u16* __restrict__ hlo_in,
        const float* __restrict__ hf_in,
        u16* __restrict__ hhi_out, u16* __restrict__ hlo_out,
        float* __restrict__ hf_out, float* __restrict__ out) {
    __shared__ float red[3][4][256];
    int tid = threadIdx.x;
    int w = tid >> 6, lane = tid & 63;
    int n = lane & 15, q = lane >> 4;
    int b0r = (blockIdx.x >> 6) * 16;
    int u0 = (blockIdx.x & 63) * 16;

    size_t aoff = (size_t)(b0r + n) * 1024 + w * 256 + q * 8;
    const u16* ahp = hhi_in + aoff;
    const u16* alp = hlo_in + aoff;
    size_t boff = (size_t)(u0 + n) * 1024 + w * 256 + q * 8;
    const u16* uzh = UThi + boff;
    const u16* uzl = UTlo + boff;
    const u16* urh = uzh + (size_t)1048576;
    const u16* url = uzl + (size_t)1048576;
    const u16* uhh = uzh + (size_t)2097152;
    const u16* uhl = uzl + (size_t)2097152;

    v4f az = {0.f, 0.f, 0.f, 0.f}, ag = az, ah = az;
    for (int kk = 0; kk < 8; ++kk) {
        v8bf Ah = *(const v8bf*)(ahp + kk * 32);
        v8bf Al = *(const v8bf*)(alp + kk * 32);
        v8bf Bzh = *(const v8bf*)(uzh + kk * 32);
        v8bf Bzl = *(const v8bf*)(uzl + kk * 32);
        v8bf Brh = *(const v8bf*)(urh + kk * 32);
        v8bf Brl = *(const v8bf*)(url + kk * 32);
        v8bf Bhh = *(const v8bf*)(uhh + kk * 32);
        v8bf Bhl = *(const v8bf*)(uhl + kk * 32);
        az = __builtin_amdgcn_mfma_f32_16x16x32_bf16(Ah, Bzh, az, 0, 0, 0);
        az = __builtin_amdgcn_mfma_f32_16x16x32_bf16(Ah, Bzl, az, 0, 0, 0);
        az = __builtin_amdgcn_mfma_f32_16x16x32_bf16(Al, Bzh, az, 0, 0, 0);
        ag = __builtin_amdgcn_mfma_f32_16x16x32_bf16(Ah, Brh, ag, 0, 0, 0);
        ag = __builtin_amdgcn_mfma_f32_16x16x32_bf16(Ah, Brl, ag, 0, 0, 0);
        ag = __builtin_amdgcn_mfma_f32_16x16x32_bf16(Al, Brh, ag, 0, 0, 0);
        ah = __builtin_amdgcn_mfma_f32_16x16x32_bf16(Ah, Bhh, ah, 0, 0, 0);
        ah = __builtin_amdgcn_mfma_f32_16x16x32_bf16(Ah, Bhl, ah, 0, 0, 0);
        ah = __builtin_amdgcn_mfma_f32_16x16x32_bf16(Al, Bhh, ah, 0, 0, 0);
    }
#pragma unroll
    for (int r = 0; r < 4; ++r) {
        int idx = (q * 4 + r) * 16 + n;  // row = quad*4+reg, col = lane&15
        red[0][w][idx] = az[r];
        red[1][w][idx] = ag[r];
        red[2][w][idx] = ah[r];
    }
    __syncthreads();

    int bl = tid >> 4, ul = tid & 15;
    float rz = red[0][0][tid] + red[0][1][tid] + red[0][2][tid] + red[0][3][tid] + b1[u0 + ul];
    float rr = red[1][0][tid] + red[1][1][tid] + red[1][2][tid] + red[1][3][tid] + b1[1024 + u0 + ul];
    float rh = red[2][0][tid] + red[2][1][tid] + red[2][2][tid] + red[2][3][tid] + b1[2048 + u0 + ul];

    int bb = b0r + bl;
    int u = u0 + ul;
    size_t bt = (size_t)bb * 128 + t;
    size_t xo = bt * 3072;
    float xz = b2f(xhi[xo + u]) + b2f(xlo[xo + u]);
    float xr = b2f(xhi[xo + 1024 + u]) + b2f(xlo[xo + 1024 + u]);
    float xh = b2f(xhi[xo + 2048 + u]) + b2f(xlo[xo + 2048 + u]);

    float z = 1.f / (1.f + expf(-(xz + rz)));
    float rg = 1.f / (1.f + expf(-(xr + rr)));
    float hh = tanhf(xh + rg * rh);
    size_t ho = (size_t)bb * 1024 + u;
    float hp = hf_in[ho];
    float hn = z * hp + (1.f - z) * hh;

    hf_out[ho] = hn;
    u16 hb_ = f2b(hn);
    hhi_out[ho] = hb_;
    hlo_out[ho] = f2b(hn - b2f(hb_));
    out[bt * 1024 + u] = hn;
}

// ---------------------------------------------------------------------------
// state = outputs[:, 127, :]
// ---------------------------------------------------------------------------
__global__ void state_kernel(const float* __restrict__ out, float* __restrict__ state) {
    int i = blockIdx.x * 256 + threadIdx.x;  // 65536
    int b = i >> 10, u = i & 1023;
    state[i] = out[((size_t)b * 128 + 127) * 1024 + u];
}

extern "C" void kernel_launch(void* const* d_in, const int* in_sizes, int n_in,
                              void* d_out, int out_size, void* d_ws, size_t ws_size,
                              hipStream_t stream) {
    const int* x = (const int*)d_in[0];
    const float* hid = (const float*)d_in[1];
    const float* E = (const float*)d_in[2];
    const float* W = (const float*)d_in[3];
    const float* U = (const float*)d_in[4];
    const float* b = (const float*)d_in[5];
    float* out = (float*)d_out;

    char* ws = (char*)d_ws;
    float* hf0 = (float*)(ws + 0);             // 262144
    float* hf1 = (float*)(ws + 262144);        // 262144
    u16* hhi0 = (u16*)(ws + 524288);           // 131072
    u16* hhi1 = (u16*)(ws + 655360);           // 131072
    u16* hlo0 = (u16*)(ws + 786432);           // 131072
    u16* hlo1 = (u16*)(ws + 917504);           // 131072
    u16* UThi = (u16*)(ws + 1048576);          // 6291456
    u16* UTlo = (u16*)(ws + 7340032);          // 6291456
    u16* WThi = (u16*)(ws + 13631488);         // 1572864
    u16* WTlo = (u16*)(ws + 15204352);         // 1572864
    u16* xhi = (u16*)(ws + 16777216);          // 50331648
    u16* xlo = (u16*)(ws + 67108864);          // 50331648  -> total 117440512 B

    prep_h<<<256, 256, 0, stream>>>(hid, hf0, hhi0, hlo0);
    transpose_split<<<dim3(96, 32), 256, 0, stream>>>(U, UThi, UTlo, 1024, 3072);
    transpose_split<<<dim3(96, 8), 256, 0, stream>>>(W, WThi, WTlo, 256, 3072);
    xin_kernel<<<1536, 256, 0, stream>>>(x, E, WThi, WTlo, b, xhi, xlo);

    for (int t = 0; t < 128; ++t) {
        const u16* hhi_i = (t & 1) ? hhi1 : hhi0;
        const u16* hlo_i = (t & 1) ? hlo1 : hlo0;
        const float* hf_i = (t & 1) ? hf1 : hf0;
        u16* hhi_o = (t & 1) ? hhi0 : hhi1;
        u16* hlo_o = (t & 1) ? hlo0 : hlo1;
        float* hf_o = (t & 1) ? hf0 : hf1;
        step_kernel<<<256, 256, 0, stream>>>(t, xhi, xlo, UThi, UTlo, b + 3072,
                                             hhi_i, hlo_i, hf_i, hhi_o, hlo_o, hf_o, out);
    }
    state_kernel<<<256, 256, 0, stream>>>(out, out + 8388608);
}